// Round 3
// baseline (235.428 us; speedup 1.0000x reference)
//
#include <hip/hip_runtime.h>
#include <stdint.h>

typedef __attribute__((ext_vector_type(8))) short bf16x8;
typedef __attribute__((ext_vector_type(4))) float f32x4;

#if __has_builtin(__builtin_amdgcn_exp2f)
#define EXP2F(x) __builtin_amdgcn_exp2f(x)
#else
#define EXP2F(x) exp2f(x)
#endif

__device__ __forceinline__ short f2bf(float f) {
    union { float f; uint32_t u; } c; c.f = f;
    return (short)((c.u + 0x7fffu + ((c.u >> 16) & 1u)) >> 16);
}

// ---- prep: Wt2g chunk-major [16 kchunks][192 cols][32 k] bf16 (LINEAR layout;
// B-frags are now read directly from global, no LDS banks -> no swizzle) + bcat[192]
__global__ void prep_kernel(const float* __restrict__ Wk, const float* __restrict__ bk,
                            const float* __restrict__ Wq, const float* __restrict__ bq,
                            const float* __restrict__ Wv, const float* __restrict__ bv,
                            short* __restrict__ Wt2g, float* __restrict__ bcat) {
    const int col = blockIdx.x;  // 0..191 (0-63=K, 64-127=Q, 128-191=V)
    const float* W; const float* bb; int c0;
    if (col < 64)       { W = Wk; bb = bk; c0 = col; }
    else if (col < 128) { W = Wq; bb = bq; c0 = col - 64; }
    else                { W = Wv; bb = bv; c0 = col - 128; }
    for (int c = threadIdx.x; c < 512; c += blockDim.x)
        Wt2g[(c >> 5) * 6144 + col * 32 + (c & 31)] = f2bf(W[(size_t)c * 64 + c0]);
    if (threadIdx.x == 0) bcat[col] = bb[c0];
}

// ---- fused per-batch kernel, 1024 threads = 16 waves ----
// Phase 1 (QKV projection), ZERO-LDS / ZERO-BARRIER:
//   16x1 wave grid; wave t exclusively owns x rows t*16..t*16+15, so each
//   lane loads its own A-fragment elements directly from global (x is read
//   exactly once from HBM). B-fragments are read per-MFMA straight from the
//   192 KB chunk-major Wt2g (L2-resident; each wave's 12 reads/chunk are a
//   contiguous, fully-coalesced 1 KB each). No inter-wave coupling at all:
//   no barriers, no global_load_lds, no manual waitcnt. Compiler pipelines
//   x one chunk ahead; 4 waves/SIMD TLP hides the rest. Phase-1 floor =
//   HBM stream of x (~21 us across 256 CUs).
// Phase 2: all-LDS causal attention (verified machinery); q-tile =
//   magic-square perm of wave so per-SIMD causal work is equal (sum=34).
// LDS (dynamic, 118784 B, phase 2 only):
//   Ks @0 (32K) | Qs @32768 (32K) | Vts @65536 (32K) | Ps @98304 (20K)
#define PSTR 40

__global__ __launch_bounds__(1024, 4) void fused_kernel(
    const float* __restrict__ x, const short* __restrict__ Wt2g,
    const float* __restrict__ bcat, float* __restrict__ out) {
    extern __shared__ __align__(16) char smem[];

    const int tid = threadIdx.x;
    const int wave = tid >> 6, lane = tid & 63;
    const int quad = lane >> 4, l16 = lane & 15;
    const int b = blockIdx.x;
    const int t = wave;                      // phase-1 m-tile

    // ================= phase 1: QKV projection (reg-only) =================
    f32x4 acc[12];
#pragma unroll
    for (int i = 0; i < 12; i++) acc[i] = (f32x4){0.f, 0.f, 0.f, 0.f};

    // lane (quad,l16) owns A[row = t*16+l16][k = kc*32 + quad*8 .. +7]
    const float* xg = x + ((size_t)b * 256 + t * 16 + l16) * 512 + quad * 8;
    const short* wg = Wt2g + l16 * 32 + quad * 8;

    f32x4 u0 = *(const f32x4*)xg;
    f32x4 u1 = *(const f32x4*)(xg + 4);
    for (int kc = 0; kc < 16; kc++) {
        f32x4 n0, n1;
        if (kc < 15) {                       // prefetch next chunk (wave-uniform branch)
            n0 = *(const f32x4*)(xg + (kc + 1) * 32);
            n1 = *(const f32x4*)(xg + (kc + 1) * 32 + 4);
        }
        bf16x8 a;
#pragma unroll
        for (int i = 0; i < 4; i++) { a[i] = f2bf(u0[i]); a[4 + i] = f2bf(u1[i]); }
        const short* wk = wg + kc * 6144;
#pragma unroll
        for (int nt = 0; nt < 12; nt++) {
            bf16x8 bf = *(const bf16x8*)(wk + nt * 512);   // contiguous 1KB/wave, L2-hot
            acc[nt] = __builtin_amdgcn_mfma_f32_16x16x32_bf16(a, bf, acc[nt], 0, 0, 0);
        }
        u0 = n0; u1 = n1;
    }

    // ---- epilogue: C-layout (row=quad*4+r, col=l16) -> swizzled phase-2 LDS ----
    short* Ks  = (short*)smem;
    short* Qs  = (short*)(smem + 32768);
    short* Vts = (short*)(smem + 65536);
    short* Ps  = (short*)(smem + 98304);
#pragma unroll
    for (int nt = 0; nt < 12; nt++) {
        const int col = nt * 16 + l16;
        const float bias = bcat[col];
        const int h = col & 63;
#pragma unroll
        for (int r = 0; r < 4; r++) {
            const short v = f2bf(acc[nt][r] + bias);
            const int row = t * 16 + quad * 4 + r;
            if (nt < 4)
                Ks[row * 64 + (((h >> 3) ^ (row & 7)) << 3) + (h & 7)] = v;
            else if (nt < 8)
                Qs[row * 64 + (((h >> 3) ^ (row & 7)) << 3) + (h & 7)] = v;
            else
                Vts[h * 256 + (((row >> 3) ^ (h & 7)) << 3) + (row & 7)] = v;
        }
    }
    __syncthreads();

    // ================= phase 2: causal attention, all-LDS =================
    // q-tile = magic-square permutation of wave: SIMD s = w&3 gets tiles
    // {s^0, 4+(s^1), 8+(s^2), 12+(s^3)} -> per-SIMD causal work equalized.
    const int qt = ((wave >> 2) << 2) | ((wave & 3) ^ (wave >> 2));
    const float sc2 = 0.125f * 1.44269504088896340736f;  // 1/sqrt(64) * log2(e)
    short* myP = Ps + wave * (16 * PSTR);

    const int qrow = qt * 16 + l16;
    const int sw = l16 & 7;
    bf16x8 qf0 = *(const bf16x8*)&Qs[qrow * 64 + ((quad ^ sw) << 3)];
    bf16x8 qf1 = *(const bf16x8*)&Qs[qrow * 64 + (((4 + quad) ^ sw) << 3)];

    f32x4 St[16];
#pragma unroll
    for (int i = 0; i < 16; i++) St[i] = (f32x4){0.f, 0.f, 0.f, 0.f};
#pragma unroll
    for (int nt = 0; nt < 16; nt++) if (nt <= qt) {
        const int krow = nt * 16 + l16;
        bf16x8 kf0 = *(const bf16x8*)&Ks[krow * 64 + ((quad ^ sw) << 3)];
        bf16x8 kf1 = *(const bf16x8*)&Ks[krow * 64 + (((4 + quad) ^ sw) << 3)];
        St[nt] = __builtin_amdgcn_mfma_f32_16x16x32_bf16(qf0, kf0, St[nt], 0, 0, 0);
        St[nt] = __builtin_amdgcn_mfma_f32_16x16x32_bf16(qf1, kf1, St[nt], 0, 0, 0);
    }

    // mask + base-2 softmax; C-layout rows = quad*4+r, col = l16
    const int rowq = qt * 16 + quad * 4;
    float mx[4], ls[4];
#pragma unroll
    for (int r = 0; r < 4; r++) mx[r] = -3.0e38f;
#pragma unroll
    for (int nt = 0; nt < 16; nt++) if (nt <= qt) {
        const int cs = nt * 16 + l16;
#pragma unroll
        for (int r = 0; r < 4; r++) {
            float s = (cs <= rowq + r) ? St[nt][r] * sc2 : -3.0e38f;
            St[nt][r] = s;
            mx[r] = fmaxf(mx[r], s);
        }
    }
#pragma unroll
    for (int d = 1; d < 16; d <<= 1)
#pragma unroll
        for (int r = 0; r < 4; r++)
            mx[r] = fmaxf(mx[r], __shfl_xor(mx[r], d, 64));
#pragma unroll
    for (int r = 0; r < 4; r++) ls[r] = 0.f;
#pragma unroll
    for (int nt = 0; nt < 16; nt++) if (nt <= qt) {
#pragma unroll
        for (int r = 0; r < 4; r++) {
            float p = EXP2F(St[nt][r] - mx[r]);
            St[nt][r] = p;                 // St[nt>qt] stays 0 == correct P
            ls[r] += p;
        }
    }
#pragma unroll
    for (int d = 1; d < 16; d <<= 1)
#pragma unroll
        for (int r = 0; r < 4; r++)
            ls[r] += __shfl_xor(ls[r], d, 64);

    // O = P V over 32-s chunks; P via wave-local LDS C->A roundtrip
    f32x4 O[4];
#pragma unroll
    for (int i = 0; i < 4; i++) O[i] = (f32x4){0.f, 0.f, 0.f, 0.f};
    const int nch = (qt + 2) >> 1;         // ceil((qt+1)/2), wave-uniform
#pragma unroll
    for (int c2 = 0; c2 < 8; c2++) if (c2 < nch) {
#pragma unroll
        for (int t2i = 0; t2i < 2; t2i++) {
            const int nt = c2 * 2 + t2i;   // St[nt]=0 beyond diagonal => P=0
#pragma unroll
            for (int r = 0; r < 4; r++)
                myP[(quad * 4 + r) * PSTR + t2i * 16 + l16] = f2bf(St[nt][r]);
        }
        bf16x8 pf = *(const bf16x8*)&myP[l16 * PSTR + quad * 8];
#pragma unroll
        for (int ht = 0; ht < 4; ht++) {
            const int h = ht * 16 + l16;
            bf16x8 vf = *(const bf16x8*)&Vts[h * 256 + (((c2 * 4 + quad) ^ (h & 7)) << 3)];
            O[ht] = __builtin_amdgcn_mfma_f32_16x16x32_bf16(pf, vf, O[ht], 0, 0, 0);
        }
    }

    float rls[4];
#pragma unroll
    for (int r = 0; r < 4; r++) rls[r] = 1.0f / ls[r];
#pragma unroll
    for (int ht = 0; ht < 4; ht++)
#pragma unroll
        for (int r = 0; r < 4; r++)
            out[((size_t)b * 256 + rowq + r) * 64 + ht * 16 + l16] = O[ht][r] * rls[r];
}

extern "C" void kernel_launch(void* const* d_in, const int* in_sizes, int n_in,
                              void* d_out, int out_size, void* d_ws, size_t ws_size,
                              hipStream_t stream) {
    const float* x  = (const float*)d_in[0];
    const float* Wk = (const float*)d_in[1];
    const float* bk = (const float*)d_in[2];
    const float* Wq = (const float*)d_in[3];
    const float* bq = (const float*)d_in[4];
    const float* Wv = (const float*)d_in[5];
    const float* bv = (const float*)d_in[6];
    float* out = (float*)d_out;

    char* ws = (char*)d_ws;
    short* Wt2g = (short*)(ws);             // 196608 B (chunk-major, linear)
    float* bcat = (float*)(ws + 196608);    // 768 B

    const int smem_bytes = 118784;          // phase-2 only; >64KB -> dynamic + attribute
    (void)hipFuncSetAttribute((const void*)fused_kernel,
                              hipFuncAttributeMaxDynamicSharedMemorySize, smem_bytes);

    prep_kernel<<<192, 256, 0, stream>>>(Wk, bk, Wq, bq, Wv, bv, Wt2g, bcat);
    fused_kernel<<<256, 1024, smem_bytes, stream>>>(x, Wt2g, bcat, out);
}

// Round 4
// 216.507 us; speedup vs baseline: 1.0874x; 1.0874x over previous
//
#include <hip/hip_runtime.h>
#include <stdint.h>

typedef __attribute__((ext_vector_type(8))) short bf16x8;
typedef __attribute__((ext_vector_type(4))) float f32x4;

#if __has_builtin(__builtin_amdgcn_exp2f)
#define EXP2F(x) __builtin_amdgcn_exp2f(x)
#else
#define EXP2F(x) exp2f(x)
#endif

__device__ __forceinline__ short f2bf(float f) {
    union { float f; uint32_t u; } c; c.f = f;
    return (short)((c.u + 0x7fffu + ((c.u >> 16) & 1u)) >> 16);
}

// async global->LDS 16B/lane: dest = wave-uniform base + lane*16 (m97/m104 semantics)
typedef __attribute__((address_space(1))) void gvoid;
typedef __attribute__((address_space(3))) void lvoid;
__device__ __forceinline__ void async_cp16(const void* g, void* l) {
    __builtin_amdgcn_global_load_lds((gvoid*)g, (lvoid*)l, 16, 0, 0);
}

// ---- prep: Wt2g chunk-major [16 kchunks][192 cols][32 k] bf16, k-slot XOR-swizzled:
// 8-short slot s of col c holds global k-slot s ^ (c&3)  (all-32-bank B reads)
__global__ void prep_kernel(const float* __restrict__ Wk, const float* __restrict__ bk,
                            const float* __restrict__ Wq, const float* __restrict__ bq,
                            const float* __restrict__ Wv, const float* __restrict__ bv,
                            short* __restrict__ Wt2g, float* __restrict__ bcat) {
    const int col = blockIdx.x;  // 0..191 (0-63=K, 64-127=Q, 128-191=V)
    const float* W; const float* bb; int c0;
    if (col < 64)       { W = Wk; bb = bk; c0 = col; }
    else if (col < 128) { W = Wq; bb = bq; c0 = col - 64; }
    else                { W = Wv; bb = bv; c0 = col - 128; }
    for (int c = threadIdx.x; c < 512; c += blockDim.x) {
        const int k5 = c & 31;
        Wt2g[(c >> 5) * 6144 + col * 32 + ((((k5 >> 3) ^ (col & 3)) << 3)) + (k5 & 7)] =
            f2bf(W[(size_t)c * 64 + c0]);
    }
    if (threadIdx.x == 0) bcat[col] = bb[c0];
}

// ---- fused per-batch kernel, 1024 threads = 16 waves ----
// Wave w owns m-tile w in phase 1 (R0 champion structure, byte-identical
// staging/loop); phase 2 q-tile = magic-square perm of wave so per-SIMD
// causal work is equal (sum t+1 = 34 per SIMD), with T5 setprio around
// the MFMA clusters.
// Phase 1: x chunk (32 KB fp32) + Wt chunk (12 KB bf16) double-buffered in LDS
// via global_load_lds_dwordx4; MFMA from LDS; no VGPR staging of global data.
// LDS layout (dynamic, 118784 B):
//   phase 1: xs0 @0 (32K) | xs1 @32768 | ws0 @65536 (12K) | ws1 @77824
//   phase 2: Ks  @0 (32K) | Qs  @32768 | Vts @65536 (32K) | Ps @98304 (20K)
#define PSTR 40

__global__ __launch_bounds__(1024, 4) void fused_kernel(
    const float* __restrict__ x, const short* __restrict__ Wt2g,
    const float* __restrict__ bcat, float* __restrict__ out) {
    extern __shared__ __align__(16) char smem[];

    const int tid = threadIdx.x;
    const int wave = tid >> 6, lane = tid & 63;
    const int quad = lane >> 4, l16 = lane & 15;
    const int b = blockIdx.x;
    const int t = wave;                      // this wave's phase-1 m-tile

    // ================= phase 1: QKV projection =================
    f32x4 acc[12];
#pragma unroll
    for (int i = 0; i < 12; i++) acc[i] = (f32x4){0.f, 0.f, 0.f, 0.f};

    const int xr = lane >> 3;        // row-within-granule (8 rows x 128B = 1KB)
    const int xsl = lane & 7;        // dest 16B slot

    // x granule i covers rows 8i..8i+7; dest slot s holds src slot s^((row&3)<<1)
#define STAGE_X(kc, bufp)                                                           \
    for (int g = 0; g < 2; g++) {                                                   \
        const int i = wave + g * 16;                                                \
        const int r = i * 8 + xr;                                                   \
        const int s = xsl ^ ((r & 3) << 1);                                         \
        async_cp16(x + ((size_t)b * 256 + r) * 512 + (kc) * 32 + s * 4,             \
                   smem + (bufp) * 32768 + i * 1024);                               \
    }
    // Wt granule = 16 cols x 64B = 1KB, plain contiguous copy (waves 0..11)
#define STAGE_W(kc, bufp)                                                           \
    if (wave < 12) {                                                                \
        async_cp16(Wt2g + (size_t)(kc) * 6144 + wave * 512 + lane * 8,              \
                   smem + 65536 + (bufp) * 12288 + wave * 1024);                    \
    }

    STAGE_X(0, 0)
    STAGE_W(0, 0)
    __syncthreads();

    const int axoff = (quad ^ (l16 & 3)) * 8;   // A 32B slot-pair after swizzle
    const int bxoff = (quad ^ (l16 & 3)) << 3;  // B 16B slot after swizzle
    const int arow = t * 16 + l16;              // local row 0..255
    for (int kc = 0; kc < 16; kc++) {
        const int buf = kc & 1;
        if (kc < 15) { STAGE_X(kc + 1, buf ^ 1) STAGE_W(kc + 1, buf ^ 1) }
        const float* xa = (const float*)(smem + buf * 32768) + arow * 32 + axoff;
        f32x4 u0 = *(const f32x4*)xa, u1 = *(const f32x4*)(xa + 4);
        bf16x8 a;
#pragma unroll
        for (int i = 0; i < 4; i++) { a[i] = f2bf(u0[i]); a[4 + i] = f2bf(u1[i]); }
        const short* wb = (const short*)(smem + 65536 + buf * 12288);
#pragma unroll
        for (int nt = 0; nt < 12; nt++) {
            bf16x8 bfrag = *(const bf16x8*)&wb[(nt * 16 + l16) * 32 + bxoff];
            acc[nt] = __builtin_amdgcn_mfma_f32_16x16x32_bf16(a, bfrag, acc[nt], 0, 0, 0);
        }
        __syncthreads();
    }

    // ---- epilogue: C-layout (row=quad*4+r, col=l16) -> swizzled phase-2 LDS ----
    short* Ks  = (short*)smem;
    short* Qs  = (short*)(smem + 32768);
    short* Vts = (short*)(smem + 65536);
    short* Ps  = (short*)(smem + 98304);
#pragma unroll
    for (int nt = 0; nt < 12; nt++) {
        const int col = nt * 16 + l16;
        const float bias = bcat[col];
        const int h = col & 63;
#pragma unroll
        for (int r = 0; r < 4; r++) {
            const short v = f2bf(acc[nt][r] + bias);
            const int row = t * 16 + quad * 4 + r;
            if (nt < 4)
                Ks[row * 64 + (((h >> 3) ^ (row & 7)) << 3) + (h & 7)] = v;
            else if (nt < 8)
                Qs[row * 64 + (((h >> 3) ^ (row & 7)) << 3) + (h & 7)] = v;
            else
                Vts[h * 256 + (((row >> 3) ^ (h & 7)) << 3) + (row & 7)] = v;
        }
    }
    __syncthreads();

    // ================= phase 2: causal attention, all-LDS =================
    // q-tile = magic-square permutation of wave: SIMD s = w&3 gets tiles
    // {s^0, 4+(s^1), 8+(s^2), 12+(s^3)} -> per-SIMD causal work equalized.
    const int qt = ((wave >> 2) << 2) | ((wave & 3) ^ (wave >> 2));
    const float sc2 = 0.125f * 1.44269504088896340736f;  // 1/sqrt(64) * log2(e)
    short* myP = Ps + wave * (16 * PSTR);

    const int qrow = qt * 16 + l16;
    const int sw = l16 & 7;
    bf16x8 qf0 = *(const bf16x8*)&Qs[qrow * 64 + ((quad ^ sw) << 3)];
    bf16x8 qf1 = *(const bf16x8*)&Qs[qrow * 64 + (((4 + quad) ^ sw) << 3)];

    f32x4 St[16];
#pragma unroll
    for (int i = 0; i < 16; i++) St[i] = (f32x4){0.f, 0.f, 0.f, 0.f};
    __builtin_amdgcn_s_setprio(1);
#pragma unroll
    for (int nt = 0; nt < 16; nt++) if (nt <= qt) {
        const int krow = nt * 16 + l16;
        bf16x8 kf0 = *(const bf16x8*)&Ks[krow * 64 + ((quad ^ sw) << 3)];
        bf16x8 kf1 = *(const bf16x8*)&Ks[krow * 64 + (((4 + quad) ^ sw) << 3)];
        St[nt] = __builtin_amdgcn_mfma_f32_16x16x32_bf16(qf0, kf0, St[nt], 0, 0, 0);
        St[nt] = __builtin_amdgcn_mfma_f32_16x16x32_bf16(qf1, kf1, St[nt], 0, 0, 0);
    }
    __builtin_amdgcn_s_setprio(0);

    // mask + base-2 softmax; C-layout rows = quad*4+r, col = l16
    const int rowq = qt * 16 + quad * 4;
    float mx[4], ls[4];
#pragma unroll
    for (int r = 0; r < 4; r++) mx[r] = -3.0e38f;
#pragma unroll
    for (int nt = 0; nt < 16; nt++) if (nt <= qt) {
        const int cs = nt * 16 + l16;
#pragma unroll
        for (int r = 0; r < 4; r++) {
            float s = (cs <= rowq + r) ? St[nt][r] * sc2 : -3.0e38f;
            St[nt][r] = s;
            mx[r] = fmaxf(mx[r], s);
        }
    }
#pragma unroll
    for (int d = 1; d < 16; d <<= 1)
#pragma unroll
        for (int r = 0; r < 4; r++)
            mx[r] = fmaxf(mx[r], __shfl_xor(mx[r], d, 64));
#pragma unroll
    for (int r = 0; r < 4; r++) ls[r] = 0.f;
#pragma unroll
    for (int nt = 0; nt < 16; nt++) if (nt <= qt) {
#pragma unroll
        for (int r = 0; r < 4; r++) {
            float p = EXP2F(St[nt][r] - mx[r]);
            St[nt][r] = p;                 // St[nt>qt] stays 0 == correct P
            ls[r] += p;
        }
    }
#pragma unroll
    for (int d = 1; d < 16; d <<= 1)
#pragma unroll
        for (int r = 0; r < 4; r++)
            ls[r] += __shfl_xor(ls[r], d, 64);

    // O = P V over 32-s chunks; P via wave-local LDS C->A roundtrip
    f32x4 O[4];
#pragma unroll
    for (int i = 0; i < 4; i++) O[i] = (f32x4){0.f, 0.f, 0.f, 0.f};
    const int nch = (qt + 2) >> 1;         // ceil((qt+1)/2), wave-uniform
    __builtin_amdgcn_s_setprio(1);
#pragma unroll
    for (int c2 = 0; c2 < 8; c2++) if (c2 < nch) {
#pragma unroll
        for (int t2i = 0; t2i < 2; t2i++) {
            const int nt = c2 * 2 + t2i;   // St[nt]=0 beyond diagonal => P=0
#pragma unroll
            for (int r = 0; r < 4; r++)
                myP[(quad * 4 + r) * PSTR + t2i * 16 + l16] = f2bf(St[nt][r]);
        }
        bf16x8 pf = *(const bf16x8*)&myP[l16 * PSTR + quad * 8];
#pragma unroll
        for (int ht = 0; ht < 4; ht++) {
            const int h = ht * 16 + l16;
            bf16x8 vf = *(const bf16x8*)&Vts[h * 256 + (((c2 * 4 + quad) ^ (h & 7)) << 3)];
            O[ht] = __builtin_amdgcn_mfma_f32_16x16x32_bf16(pf, vf, O[ht], 0, 0, 0);
        }
    }
    __builtin_amdgcn_s_setprio(0);

    float rls[4];
#pragma unroll
    for (int r = 0; r < 4; r++) rls[r] = 1.0f / ls[r];
#pragma unroll
    for (int ht = 0; ht < 4; ht++)
#pragma unroll
        for (int r = 0; r < 4; r++)
            out[((size_t)b * 256 + rowq + r) * 64 + ht * 16 + l16] = O[ht][r] * rls[r];
#undef STAGE_X
#undef STAGE_W
}

extern "C" void kernel_launch(void* const* d_in, const int* in_sizes, int n_in,
                              void* d_out, int out_size, void* d_ws, size_t ws_size,
                              hipStream_t stream) {
    const float* x  = (const float*)d_in[0];
    const float* Wk = (const float*)d_in[1];
    const float* bk = (const float*)d_in[2];
    const float* Wq = (const float*)d_in[3];
    const float* bq = (const float*)d_in[4];
    const float* Wv = (const float*)d_in[5];
    const float* bv = (const float*)d_in[6];
    float* out = (float*)d_out;

    char* ws = (char*)d_ws;
    short* Wt2g = (short*)(ws);             // 196608 B (chunk-major, k-slot swizzled)
    float* bcat = (float*)(ws + 196608);    // 768 B

    const int smem_bytes = 118784;          // >64KB -> dynamic + attribute
    (void)hipFuncSetAttribute((const void*)fused_kernel,
                              hipFuncAttributeMaxDynamicSharedMemorySize, smem_bytes);

    prep_kernel<<<192, 256, 0, stream>>>(Wk, bk, Wq, bq, Wv, bv, Wt2g, bcat);
    fused_kernel<<<256, 1024, smem_bytes, stream>>>(x, Wt2g, bcat, out);
}